// Round 12
// baseline (48.969 us; speedup 1.0000x reference)
//
#include <hip/hip_runtime.h>

using iv4 = __attribute__((ext_vector_type(4))) int;
using fv4 = __attribute__((ext_vector_type(4))) float;
using usv4 = __attribute__((ext_vector_type(4))) unsigned short;
using llv2 = __attribute__((ext_vector_type(2))) long long;

#define RPT 2            // fallback kernel: rows per thread
#define LDS_ITER 8       // LDS kernel: rows per thread per stride-step
#define LDS_BLK 1024     // LDS kernel block size

__device__ __forceinline__ int pid_of(const int* __restrict__ s_off, int P, int row) {
    int c = -1;
    for (int k = 0; k <= P; ++k) c += (s_off[k] <= row) ? 1 : 0;
    return min(max(c, 0), P - 1);
}

__device__ __forceinline__ unsigned long long pack_at8(float x, float y, float z,
                                                       int uid_in) {
    int xq = (int)rintf((x + 32.0f) * 512.0f);
    int yq = (int)rintf((y + 32.0f) * 512.0f);
    int zq = (int)rintf((z + 32.0f) * 256.0f);
    xq = min(max(xq, 0), 32767);
    yq = min(max(yq, 0), 32767);
    zq = min(max(zq, 0), 16383);
    const unsigned uid = (unsigned)uid_in & 0xFFFFFu;
    const unsigned lo = (unsigned)xq | ((unsigned)yq << 15) | ((unsigned)(zq & 3) << 30);
    const unsigned hi = (unsigned)(zq >> 2) | (uid << 12);
    return (unsigned long long)lo | ((unsigned long long)hi << 32);
}

__device__ __forceinline__ unsigned short pack_hv2(float Kc, float x0, int per) {
    int kq  = (int)rintf(Kc * 64.0f);
    int xq0 = (int)rintf(x0 * 32.0f);
    kq  = min(max(kq, 0), 255);
    xq0 = min(max(xq0, 0), 63);
    return (unsigned short)((unsigned)kq | ((unsigned)xq0 << 8)
                            | ((unsigned)(per - 1) << 14));
}

// Vectorized prep: 4 entries/thread. Requires H%4==0 && PA%4==0.
__global__ void prep_vec_kernel(const float* __restrict__ coords,
                                const int* __restrict__ uids,
                                const int* __restrict__ hkeys,
                                const float* __restrict__ hvals,
                                int PA, int H,
                                unsigned long long* __restrict__ at8,
                                unsigned short* __restrict__ hv2tab,
                                int* __restrict__ counter)
{
    if (blockIdx.x == 0 && threadIdx.x == 0) *counter = 0;   // for last-block final
    const int stride4 = gridDim.x * blockDim.x;
    const int n4 = H >> 2;
    for (int q = blockIdx.x * blockDim.x + threadIdx.x; q < n4; q += stride4) {
        const int t0 = q * 4;
        if (t0 < PA) {
            const fv4 c0 = reinterpret_cast<const fv4*>(coords)[3 * q];
            const fv4 c1 = reinterpret_cast<const fv4*>(coords)[3 * q + 1];
            const fv4 c2 = reinterpret_cast<const fv4*>(coords)[3 * q + 2];
            const iv4 u  = reinterpret_cast<const iv4*>(uids)[q];
            llv2 w0, w1;
            w0.x = (long long)pack_at8(c0.x, c0.y, c0.z, u.x);
            w0.y = (long long)pack_at8(c0.w, c1.x, c1.y, u.y);
            w1.x = (long long)pack_at8(c1.z, c1.w, c2.x, u.z);
            w1.y = (long long)pack_at8(c2.y, c2.z, c2.w, u.w);
            reinterpret_cast<llv2*>(at8)[2 * q]     = w0;
            reinterpret_cast<llv2*>(at8)[2 * q + 1] = w1;
        }
        const iv4 hk = reinterpret_cast<const iv4*>(hkeys)[q];
        const fv4 h0 = reinterpret_cast<const fv4*>(hvals)[3 * q];
        const fv4 h1 = reinterpret_cast<const fv4*>(hvals)[3 * q + 1];
        const fv4 h2 = reinterpret_cast<const fv4*>(hvals)[3 * q + 2];
        usv4 e;
        {
            const bool hit = (hk.x == t0);
            e.x = pack_hv2(hit ? h0.x : 1.0f, hit ? h0.y : 0.0f,
                           hit ? (int)(rintf(h0.z * 3.0f) + 1.0f) : 1);
        }
        {
            const bool hit = (hk.y == t0 + 1);
            e.y = pack_hv2(hit ? h0.w : 1.0f, hit ? h1.x : 0.0f,
                           hit ? (int)(rintf(h1.y * 3.0f) + 1.0f) : 1);
        }
        {
            const bool hit = (hk.z == t0 + 2);
            e.z = pack_hv2(hit ? h1.z : 1.0f, hit ? h1.w : 0.0f,
                           hit ? (int)(rintf(h2.x * 3.0f) + 1.0f) : 1);
        }
        {
            const bool hit = (hk.w == t0 + 3);
            e.w = pack_hv2(hit ? h2.y : 1.0f, hit ? h2.z : 0.0f,
                           hit ? (int)(rintf(h2.w * 3.0f) + 1.0f) : 1);
        }
        reinterpret_cast<usv4*>(hv2tab)[q] = e;
    }
}

// Scalar prep (general shapes).
__global__ void prep_kernel(const float* __restrict__ coords,
                            const int* __restrict__ uids,
                            const int* __restrict__ hkeys,
                            const float* __restrict__ hvals,
                            int PA, int H,
                            unsigned long long* __restrict__ at8,
                            unsigned short* __restrict__ hv2tab,
                            int* __restrict__ counter)
{
    if (blockIdx.x == 0 && threadIdx.x == 0) *counter = 0;
    const int stride = gridDim.x * blockDim.x;
    for (int t = blockIdx.x * blockDim.x + threadIdx.x; t < H; t += stride) {
        if (t < PA)
            at8[t] = pack_at8(coords[3 * t], coords[3 * t + 1], coords[3 * t + 2],
                              uids[t]);
        const bool hit = (hkeys[t] == t);
        hv2tab[t] = pack_hv2(hit ? hvals[3 * t] : 1.0f,
                             hit ? hvals[3 * t + 1] : 0.0f,
                             hit ? (int)(rintf(hvals[3 * t + 2] * 3.0f) + 1.0f) : 1);
    }
}

__device__ __forceinline__ float energy_row(int nat, fv4 R0, fv4 R1, fv4 R2, fv4 R3,
                                            float Kc, float x0, float per)
{
    const float eps = 1e-6f;
    if (nat == 2) {
        const float dx = R1.x - R0.x, dy = R1.y - R0.y, dz = R1.z - R0.z;
        const float d = sqrtf(dx * dx + dy * dy + dz * dz + eps);
        const float t = d - x0;
        return Kc * t * t;
    } else if (nat == 3) {
        const float ux = R0.x - R1.x, uy = R0.y - R1.y, uz = R0.z - R1.z;
        const float vx = R2.x - R1.x, vy = R2.y - R1.y, vz = R2.z - R1.z;
        const float uv = ux * vx + uy * vy + uz * vz;
        const float uu = ux * ux + uy * uy + uz * uz;
        const float vv = vx * vx + vy * vy + vz * vz;
        float cosang = uv / (sqrtf(uu + eps) * sqrtf(vv + eps));
        cosang = fminf(fmaxf(cosang, -1.0f + 1e-6f), 1.0f - 1e-6f);
        const float t = acosf(cosang) - x0;
        return Kc * t * t;
    } else {
        const float b1x = R1.x - R0.x, b1y = R1.y - R0.y, b1z = R1.z - R0.z;
        const float b2x = R2.x - R1.x, b2y = R2.y - R1.y, b2z = R2.z - R1.z;
        const float b3x = R3.x - R2.x, b3y = R3.y - R2.y, b3z = R3.z - R2.z;
        const float n1x = b1y * b2z - b1z * b2y;
        const float n1y = b1z * b2x - b1x * b2z;
        const float n1z = b1x * b2y - b1y * b2x;
        const float n2x = b2y * b3z - b2z * b3y;
        const float n2y = b2z * b3x - b2x * b3z;
        const float n2z = b2x * b3y - b2y * b3x;
        const float b2n = sqrtf(b2x * b2x + b2y * b2y + b2z * b2z + eps);
        const float bux = b2x / b2n, buy = b2y / b2n, buz = b2z / b2n;
        const float m1x = n1y * buz - n1z * buy;
        const float m1y = n1z * bux - n1x * buz;
        const float m1z = n1x * buy - n1y * bux;
        const float yv = m1x * n2x + m1y * n2y + m1z * n2z;
        const float xv = n1x * n2x + n1y * n2y + n1z * n2z + eps;
        const float phi = atan2f(yv, xv);
        return Kc * (1.0f + cosf(per * phi - x0));
    }
}

__device__ __forceinline__ fv4 unpack_pos(unsigned long long a) {
    const unsigned lo = (unsigned)a, hi = (unsigned)(a >> 32);
    fv4 r;
    r.x = (float)(int)(lo & 0x7FFFu) * (1.0f / 512.0f) - 32.0f;
    r.y = (float)(int)((lo >> 15) & 0x7FFFu) * (1.0f / 512.0f) - 32.0f;
    r.z = (float)(int)(((hi & 0xFFFu) << 2) | (lo >> 30)) * (1.0f / 256.0f) - 32.0f;
    r.w = 0.0f;
    return r;
}
__device__ __forceinline__ unsigned unpack_uid(unsigned long long a) {
    return (unsigned)(a >> 32) >> 12;
}
__device__ __forceinline__ float hv_energy(unsigned w, int nat,
                                           fv4 R0, fv4 R1, fv4 R2, fv4 R3) {
    const float Kc  = (float)(w & 0xFFu) * (1.0f / 64.0f);
    const float x0  = (float)((w >> 8) & 0x3Fu) * (1.0f / 32.0f);
    const float per = (float)((w >> 14) + 1u);
    return energy_row(nat, R0, R1, R2, R3, Kc, x0, per);
}

// ================= LDS-slab main kernel (+ fused last-block final) =================
__launch_bounds__(LDS_BLK, 1)
__global__ void cart_lds_kernel(
    const unsigned long long* __restrict__ at8,    // [P*A]
    const unsigned short* __restrict__ hv2tab,     // [H]
    const int* __restrict__ subs,                  // [NSUB,4]
    const int* __restrict__ offs,                  // [P+1]
    float*     __restrict__ partials,              // [P*nchunk]
    int*       __restrict__ counter,               // zeroed by prep
    float*     __restrict__ out,                   // [P]
    int nchunk, int nsub, int P, int A, unsigned H)
{
    __shared__ unsigned long long slab[16384];     // 128 KiB
    __shared__ float s_w[LDS_BLK / 64];
    __shared__ float s_pose[16];
    __shared__ int s_last;

    const int p = blockIdx.x / nchunk;
    const int c = blockIdx.x % nchunk;
    const int lo = (p == 0) ? 0 : offs[p];
    const int hi = (p == P - 1) ? nsub : offs[p + 1];

    // Stage pose slab (coalesced).
    const unsigned long long* __restrict__ src = at8 + (long)p * A;
    for (int t = threadIdx.x; t < A; t += LDS_BLK)
        slab[t] = src[t];
    __syncthreads();

    const unsigned hmask = H - 1u;
    const bool pow2 = (H & hmask) == 0u;
    const int RPB = LDS_BLK * LDS_ITER;

    float acc = 0.0f;
    for (int start = lo + c * RPB; start < hi; start += nchunk * RPB) {
        #pragma unroll
        for (int k = 0; k < LDS_ITER; ++k) {
            const int row = start + k * LDS_BLK + (int)threadIdx.x;
            const bool a = row < hi;
            const int rr = a ? row : (nsub - 1);
            const iv4 sg = __builtin_nontemporal_load(
                reinterpret_cast<const iv4*>(subs) + rr);
            const int nat = (sg.x >= 0) + (sg.y >= 0) + (sg.z >= 0) + (sg.w >= 0);
            const unsigned long long a0 = slab[max(sg.x, 0)];
            const unsigned long long a1 = slab[max(sg.y, 0)];
            const unsigned long long a2 = (sg.z >= 0) ? slab[sg.z] : 0ull;
            const unsigned long long a3 = (sg.w >= 0) ? slab[sg.w] : 0ull;
            const unsigned u0 = (sg.x >= 0) ? unpack_uid(a0) : 0u;
            const unsigned u1 = (sg.y >= 0) ? unpack_uid(a1) : 0u;
            const unsigned u2 = (sg.z >= 0) ? unpack_uid(a2) : 0u;
            const unsigned u3 = (sg.w >= 0) ? unpack_uid(a3) : 0u;
            const unsigned kk = u0 * 3u + u1 * 5u + u2 * 7u + u3 * 11u + (unsigned)nat;
            const unsigned key = pow2 ? (kk & hmask) : (kk % H);
            const unsigned w = (unsigned)hv2tab[key];
            const float e = hv_energy(w, nat, unpack_pos(a0), unpack_pos(a1),
                                      unpack_pos(a2), unpack_pos(a3));
            acc += a ? e : 0.0f;
        }
    }

    // Block reduction -> one float.
    #pragma unroll
    for (int off = 1; off < 64; off <<= 1) acc += __shfl_xor(acc, off);
    const int wid = threadIdx.x >> 6, lane = threadIdx.x & 63;
    if (lane == 0) s_w[wid] = acc;
    __syncthreads();
    if (threadIdx.x == 0) {
        float s = 0.0f;
        #pragma unroll
        for (int w = 0; w < LDS_BLK / 64; ++w) s += s_w[w];
        // Device-scope release handoff (XCD-safe), then signal.
        __hip_atomic_store(&partials[blockIdx.x], s, __ATOMIC_RELEASE,
                           __HIP_MEMORY_SCOPE_AGENT);
        const int old = __hip_atomic_fetch_add(counter, 1, __ATOMIC_ACQ_REL,
                                               __HIP_MEMORY_SCOPE_AGENT);
        s_last = (old == (int)gridDim.x - 1) ? 1 : 0;
    }
    __syncthreads();

    // Last block: fused final reduction (saves one kernel launch).
    if (s_last) {
        if (threadIdx.x < 16) s_pose[threadIdx.x] = 0.0f;
        __syncthreads();
        const int ngrid = (int)gridDim.x;
        for (int j = threadIdx.x; j < ngrid; j += LDS_BLK) {
            const float v = __hip_atomic_load(&partials[j], __ATOMIC_ACQUIRE,
                                              __HIP_MEMORY_SCOPE_AGENT);
            atomicAdd(&s_pose[j / nchunk], v);     // LDS atomic
        }
        __syncthreads();
        if (threadIdx.x < P) out[threadIdx.x] = s_pose[threadIdx.x];
    }
}

// ================= round-9 kernel (fallback when slab > LDS) =================
__launch_bounds__(256)
__global__ void cart_main_kernel(
    const unsigned long long* __restrict__ at8,
    const unsigned short* __restrict__ hv2tab,
    const int* __restrict__ subs,
    const int* __restrict__ offs,
    float*     __restrict__ partials,              // [16, nblk]
    int nblk, int nsub, int P, int A, unsigned H)
{
    __shared__ int s_off[32];
    __shared__ float s_part[64];
    for (int t = threadIdx.x; t < P + 1; t += blockDim.x) s_off[t] = offs[t];
    if (threadIdx.x < 64) s_part[threadIdx.x] = 0.0f;
    __syncthreads();

    const int lane = threadIdx.x & 63;
    const int wid  = threadIdx.x >> 6;
    const int wbase = (blockIdx.x * 4 + wid) * (64 * RPT);
    const unsigned hmask = H - 1u;
    const bool pow2 = (H & hmask) == 0u;

    const int pid_lo = pid_of(s_off, P, min(wbase, nsub - 1));
    const int pid_hi = pid_of(s_off, P, min(wbase + 64 * RPT - 1, nsub - 1));
    const bool wuni = (pid_lo == pid_hi);

    iv4 sg[RPT];
    int nat[RPT], pidr[RPT];
    bool act[RPT];
    unsigned long long a0[RPT], a1[RPT], a2[RPT], a3[RPT];

    #pragma unroll
    for (int k = 0; k < RPT; ++k) {
        const int row = wbase + k * 64 + lane;
        act[k] = row < nsub;
        const int rr = act[k] ? row : nsub - 1;
        sg[k] = __builtin_nontemporal_load(reinterpret_cast<const iv4*>(subs) + rr);
        nat[k] = (sg[k].x >= 0) + (sg[k].y >= 0) + (sg[k].z >= 0) + (sg[k].w >= 0);
        pidr[k] = wuni ? pid_lo : pid_of(s_off, P, rr);
        const unsigned long long* __restrict__ base = at8 + (long)pidr[k] * A;
        a0[k] = base[max(sg[k].x, 0)];
        a1[k] = base[max(sg[k].y, 0)];
        a2[k] = (sg[k].z >= 0) ? base[sg[k].z] : 0ull;
        a3[k] = (sg[k].w >= 0) ? base[sg[k].w] : 0ull;
    }

    unsigned hvw[RPT];
    #pragma unroll
    for (int k = 0; k < RPT; ++k) {
        const unsigned u0 = (sg[k].x >= 0) ? unpack_uid(a0[k]) : 0u;
        const unsigned u1 = (sg[k].y >= 0) ? unpack_uid(a1[k]) : 0u;
        const unsigned u2 = (sg[k].z >= 0) ? unpack_uid(a2[k]) : 0u;
        const unsigned u3 = (sg[k].w >= 0) ? unpack_uid(a3[k]) : 0u;
        const unsigned kk = u0 * 3u + u1 * 5u + u2 * 7u + u3 * 11u + (unsigned)nat[k];
        const unsigned key = pow2 ? (kk & hmask) : (kk % H);
        hvw[k] = (unsigned)hv2tab[key];
    }

    float ek[RPT], esum = 0.0f;
    #pragma unroll
    for (int k = 0; k < RPT; ++k) {
        float e = hv_energy(hvw[k], nat[k], unpack_pos(a0[k]), unpack_pos(a1[k]),
                            unpack_pos(a2[k]), unpack_pos(a3[k]));
        e = act[k] ? e : 0.0f;
        ek[k] = e;
        esum += e;
    }

    if (wuni) {
        #pragma unroll
        for (int off = 1; off < 64; off <<= 1) esum += __shfl_xor(esum, off);
        if (lane == 0) s_part[wid * 16 + pid_lo] += esum;
    } else {
        #pragma unroll
        for (int k = 0; k < RPT; ++k)
            if (act[k]) atomicAdd(&s_part[wid * 16 + pidr[k]], ek[k]);
    }
    __syncthreads();
    if (threadIdx.x < 16) {
        const float p = s_part[threadIdx.x] + s_part[16 + threadIdx.x]
                      + s_part[32 + threadIdx.x] + s_part[48 + threadIdx.x];
        partials[(long)threadIdx.x * nblk + blockIdx.x] = p;
    }
}

__launch_bounds__(256)
__global__ void final_reduce_kernel(const float* __restrict__ partials, int nblk,
                                    float* __restrict__ out)
{
    const int p = blockIdx.x;
    float s = 0.0f;
    for (int j = threadIdx.x; j < nblk; j += blockDim.x)
        s += partials[(long)p * nblk + j];
    #pragma unroll
    for (int off = 1; off < 64; off <<= 1) s += __shfl_xor(s, off);
    __shared__ float sw[4];
    const int wid = threadIdx.x >> 6, lane = threadIdx.x & 63;
    if (lane == 0) sw[wid] = s;
    __syncthreads();
    if (threadIdx.x == 0) out[p] = sw[0] + sw[1] + sw[2] + sw[3];
}

// ---------- fallback path (tiny workspace): direct atomics, full precision ----------
__global__ void init_kernel(float* __restrict__ out, int n) {
    int i = blockIdx.x * blockDim.x + threadIdx.x;
    if (i < n) out[i] = 0.0f;
}
__device__ __forceinline__ float3 ld3(const float* __restrict__ p) {
    return make_float3(p[0], p[1], p[2]);
}
__launch_bounds__(256)
__global__ void cart_bonded_fallback_kernel(
    const float* __restrict__ coords, const int* __restrict__ uids,
    const int* __restrict__ hkeys, const float* __restrict__ hvals,
    const int* __restrict__ subs, const int* __restrict__ offs,
    float* __restrict__ out, int nsub, int P, int A, unsigned H)
{
    __shared__ int s_off[32];
    for (int t = threadIdx.x; t < P + 1; t += blockDim.x) s_off[t] = offs[t];
    __syncthreads();
    const int i = blockIdx.x * blockDim.x + threadIdx.x;
    if (i >= nsub) return;
    const iv4 sg = reinterpret_cast<const iv4*>(subs)[i];
    const int nat = (sg.x >= 0) + (sg.y >= 0) + (sg.z >= 0) + (sg.w >= 0);
    const int pid = pid_of(s_off, P, i);
    const int i0 = max(sg.x, 0), i1 = max(sg.y, 0), i2 = max(sg.z, 0), i3 = max(sg.w, 0);
    const int* ub = uids + (long)pid * A;
    const unsigned u0 = (sg.x >= 0) ? (unsigned)ub[i0] : 0u;
    const unsigned u1 = (sg.y >= 0) ? (unsigned)ub[i1] : 0u;
    const unsigned u2 = (sg.z >= 0) ? (unsigned)ub[i2] : 0u;
    const unsigned u3 = (sg.w >= 0) ? (unsigned)ub[i3] : 0u;
    unsigned k = u0 * 3u + u1 * 5u + u2 * 7u + u3 * 11u + (unsigned)nat;
    const unsigned key = ((H & (H - 1u)) == 0u) ? (k & (H - 1u)) : (k % H);
    const bool hit = (hkeys[key] == (int)key);
    float Kc = 1.0f, x0 = 0.0f, per = 1.0f;
    if (hit) {
        const float* hvp = hvals + 3L * key;
        Kc = hvp[0]; x0 = hvp[1]; per = rintf(hvp[2] * 3.0f) + 1.0f;
    }
    const float* cb = coords + (long)pid * (long)A * 3L;
    fv4 R0, R1, R2, R3;
    float3 q;
    q = ld3(cb + 3L * i0); R0.x = q.x; R0.y = q.y; R0.z = q.z;
    q = ld3(cb + 3L * i1); R1.x = q.x; R1.y = q.y; R1.z = q.z;
    q = ld3(cb + 3L * i2); R2.x = q.x; R2.y = q.y; R2.z = q.z;
    q = ld3(cb + 3L * i3); R3.x = q.x; R3.y = q.y; R3.z = q.z;
    const float e = energy_row(nat, R0, R1, R2, R3, Kc, x0, per);
    atomicAdd(&out[pid], e);
}

extern "C" void kernel_launch(void* const* d_in, const int* in_sizes, int n_in,
                              void* d_out, int out_size, void* d_ws, size_t ws_size,
                              hipStream_t stream) {
    const float* coords = (const float*)d_in[0];
    const int*   uids   = (const int*)d_in[5];
    const int*   hkeys  = (const int*)d_in[6];
    const float* hvals  = (const float*)d_in[7];
    const int*   subs   = (const int*)d_in[8];
    const int*   offs   = (const int*)d_in[9];
    float* out = (float*)d_out;

    const int P    = in_sizes[9] - 1;        // 16
    const int A    = in_sizes[5] / P;        // 16384
    const int H    = in_sizes[6];            // 1<<20
    const int nsub = in_sizes[8] / 4;        // 2,000,000
    const int PA   = P * A;

    // LDS-path geometry
    const int RPB = LDS_BLK * LDS_ITER;                 // 8192
    const int avg = (nsub + P - 1) / max(P, 1);
    int nchunk = (avg + RPB - 1) / RPB;
    if (nchunk < 1) nchunk = 1;
    const int ngrid = P * nchunk;                       // 256 for default shape

    // r9-path geometry
    const int nblk = (nsub + 256 * RPT - 1) / (256 * RPT);

    // ws layout (256-aligned): at8 | hv2tab | partials | counter
    const size_t off_at8  = 0;
    const size_t off_hv2  = off_at8 + (size_t)PA * 8;
    const size_t off_part = (off_hv2 + (size_t)H * 2 + 255) & ~(size_t)255;
    const size_t part_a   = (size_t)ngrid * 4;
    const size_t part_b   = (size_t)16 * nblk * 4;
    const size_t part_sz  = (part_a > part_b ? part_a : part_b);
    const size_t off_cnt  = (off_part + part_sz + 255) & ~(size_t)255;
    const size_t need     = off_cnt + 256;

    if (ws_size >= need && P >= 1 && P <= 16 && H <= (1 << 20)) {
        unsigned long long* at8      = (unsigned long long*)((char*)d_ws + off_at8);
        unsigned short*     hv2tab   = (unsigned short*)((char*)d_ws + off_hv2);
        float*              partials = (float*)((char*)d_ws + off_part);
        int*                counter  = (int*)((char*)d_ws + off_cnt);

        if ((H & 3) == 0 && (PA & 3) == 0)
            prep_vec_kernel<<<2048, 256, 0, stream>>>(coords, uids, hkeys, hvals,
                                                      PA, H, at8, hv2tab, counter);
        else
            prep_kernel<<<4096, 256, 0, stream>>>(coords, uids, hkeys, hvals,
                                                  PA, H, at8, hv2tab, counter);

        if ((size_t)A * 8 <= 131072 && ngrid >= 1) {
            cart_lds_kernel<<<ngrid, LDS_BLK, 0, stream>>>(
                at8, hv2tab, subs, offs, partials, counter, out,
                nchunk, nsub, P, A, (unsigned)H);
        } else {
            cart_main_kernel<<<nblk, 256, 0, stream>>>(
                at8, hv2tab, subs, offs, partials, nblk, nsub, P, A, (unsigned)H);
            final_reduce_kernel<<<P, 256, 0, stream>>>(partials, nblk, out);
        }
    } else {
        init_kernel<<<1, 64, 0, stream>>>(out, out_size);
        const int grid = (nsub + 255) / 256;
        cart_bonded_fallback_kernel<<<grid, 256, 0, stream>>>(
            coords, uids, hkeys, hvals, subs, offs, out, nsub, P, A, (unsigned)H);
    }
}

// Round 13
// 38.014 us; speedup vs baseline: 1.2882x; 1.2882x over previous
//
#include <hip/hip_runtime.h>

using iv4 = __attribute__((ext_vector_type(4))) int;
using fv4 = __attribute__((ext_vector_type(4))) float;
using usv4 = __attribute__((ext_vector_type(4))) unsigned short;
using llv2 = __attribute__((ext_vector_type(2))) long long;

#define RPT 2            // fallback kernel: rows per thread
#define LDS_ITER 8       // LDS kernel: rows per thread per stride-step
#define LDS_BLK 1024     // LDS kernel block size

__device__ __forceinline__ int pid_of(const int* __restrict__ s_off, int P, int row) {
    int c = -1;
    for (int k = 0; k <= P; ++k) c += (s_off[k] <= row) ? 1 : 0;
    return min(max(c, 0), P - 1);
}

__device__ __forceinline__ unsigned long long pack_at8(float x, float y, float z,
                                                       int uid_in) {
    int xq = (int)rintf((x + 32.0f) * 512.0f);
    int yq = (int)rintf((y + 32.0f) * 512.0f);
    int zq = (int)rintf((z + 32.0f) * 256.0f);
    xq = min(max(xq, 0), 32767);
    yq = min(max(yq, 0), 32767);
    zq = min(max(zq, 0), 16383);
    const unsigned uid = (unsigned)uid_in & 0xFFFFFu;
    const unsigned lo = (unsigned)xq | ((unsigned)yq << 15) | ((unsigned)(zq & 3) << 30);
    const unsigned hi = (unsigned)(zq >> 2) | (uid << 12);
    return (unsigned long long)lo | ((unsigned long long)hi << 32);
}

__device__ __forceinline__ unsigned short pack_hv2(float Kc, float x0, int per) {
    int kq  = (int)rintf(Kc * 64.0f);
    int xq0 = (int)rintf(x0 * 32.0f);
    kq  = min(max(kq, 0), 255);
    xq0 = min(max(xq0, 0), 63);
    return (unsigned short)((unsigned)kq | ((unsigned)xq0 << 8)
                            | ((unsigned)(per - 1) << 14));
}

// Vectorized prep: 4 entries/thread. Requires H%4==0 && PA%4==0.
__global__ void prep_vec_kernel(const float* __restrict__ coords,
                                const int* __restrict__ uids,
                                const int* __restrict__ hkeys,
                                const float* __restrict__ hvals,
                                int PA, int H,
                                unsigned long long* __restrict__ at8,
                                unsigned short* __restrict__ hv2tab)
{
    const int stride4 = gridDim.x * blockDim.x;
    const int n4 = H >> 2;
    for (int q = blockIdx.x * blockDim.x + threadIdx.x; q < n4; q += stride4) {
        const int t0 = q * 4;
        if (t0 < PA) {
            const fv4 c0 = reinterpret_cast<const fv4*>(coords)[3 * q];
            const fv4 c1 = reinterpret_cast<const fv4*>(coords)[3 * q + 1];
            const fv4 c2 = reinterpret_cast<const fv4*>(coords)[3 * q + 2];
            const iv4 u  = reinterpret_cast<const iv4*>(uids)[q];
            llv2 w0, w1;
            w0.x = (long long)pack_at8(c0.x, c0.y, c0.z, u.x);
            w0.y = (long long)pack_at8(c0.w, c1.x, c1.y, u.y);
            w1.x = (long long)pack_at8(c1.z, c1.w, c2.x, u.z);
            w1.y = (long long)pack_at8(c2.y, c2.z, c2.w, u.w);
            reinterpret_cast<llv2*>(at8)[2 * q]     = w0;
            reinterpret_cast<llv2*>(at8)[2 * q + 1] = w1;
        }
        const iv4 hk = reinterpret_cast<const iv4*>(hkeys)[q];
        const fv4 h0 = reinterpret_cast<const fv4*>(hvals)[3 * q];
        const fv4 h1 = reinterpret_cast<const fv4*>(hvals)[3 * q + 1];
        const fv4 h2 = reinterpret_cast<const fv4*>(hvals)[3 * q + 2];
        usv4 e;
        {
            const bool hit = (hk.x == t0);
            e.x = pack_hv2(hit ? h0.x : 1.0f, hit ? h0.y : 0.0f,
                           hit ? (int)(rintf(h0.z * 3.0f) + 1.0f) : 1);
        }
        {
            const bool hit = (hk.y == t0 + 1);
            e.y = pack_hv2(hit ? h0.w : 1.0f, hit ? h1.x : 0.0f,
                           hit ? (int)(rintf(h1.y * 3.0f) + 1.0f) : 1);
        }
        {
            const bool hit = (hk.z == t0 + 2);
            e.z = pack_hv2(hit ? h1.z : 1.0f, hit ? h1.w : 0.0f,
                           hit ? (int)(rintf(h2.x * 3.0f) + 1.0f) : 1);
        }
        {
            const bool hit = (hk.w == t0 + 3);
            e.w = pack_hv2(hit ? h2.y : 1.0f, hit ? h2.z : 0.0f,
                           hit ? (int)(rintf(h2.w * 3.0f) + 1.0f) : 1);
        }
        reinterpret_cast<usv4*>(hv2tab)[q] = e;
    }
}

// Scalar prep (general shapes).
__global__ void prep_kernel(const float* __restrict__ coords,
                            const int* __restrict__ uids,
                            const int* __restrict__ hkeys,
                            const float* __restrict__ hvals,
                            int PA, int H,
                            unsigned long long* __restrict__ at8,
                            unsigned short* __restrict__ hv2tab)
{
    const int stride = gridDim.x * blockDim.x;
    for (int t = blockIdx.x * blockDim.x + threadIdx.x; t < H; t += stride) {
        if (t < PA)
            at8[t] = pack_at8(coords[3 * t], coords[3 * t + 1], coords[3 * t + 2],
                              uids[t]);
        const bool hit = (hkeys[t] == t);
        hv2tab[t] = pack_hv2(hit ? hvals[3 * t] : 1.0f,
                             hit ? hvals[3 * t + 1] : 0.0f,
                             hit ? (int)(rintf(hvals[3 * t + 2] * 3.0f) + 1.0f) : 1);
    }
}

__device__ __forceinline__ float energy_row(int nat, fv4 R0, fv4 R1, fv4 R2, fv4 R3,
                                            float Kc, float x0, float per)
{
    const float eps = 1e-6f;
    if (nat == 2) {
        const float dx = R1.x - R0.x, dy = R1.y - R0.y, dz = R1.z - R0.z;
        const float d = sqrtf(dx * dx + dy * dy + dz * dz + eps);
        const float t = d - x0;
        return Kc * t * t;
    } else if (nat == 3) {
        const float ux = R0.x - R1.x, uy = R0.y - R1.y, uz = R0.z - R1.z;
        const float vx = R2.x - R1.x, vy = R2.y - R1.y, vz = R2.z - R1.z;
        const float uv = ux * vx + uy * vy + uz * vz;
        const float uu = ux * ux + uy * uy + uz * uz;
        const float vv = vx * vx + vy * vy + vz * vz;
        float cosang = uv / (sqrtf(uu + eps) * sqrtf(vv + eps));
        cosang = fminf(fmaxf(cosang, -1.0f + 1e-6f), 1.0f - 1e-6f);
        const float t = acosf(cosang) - x0;
        return Kc * t * t;
    } else {
        const float b1x = R1.x - R0.x, b1y = R1.y - R0.y, b1z = R1.z - R0.z;
        const float b2x = R2.x - R1.x, b2y = R2.y - R1.y, b2z = R2.z - R1.z;
        const float b3x = R3.x - R2.x, b3y = R3.y - R2.y, b3z = R3.z - R2.z;
        const float n1x = b1y * b2z - b1z * b2y;
        const float n1y = b1z * b2x - b1x * b2z;
        const float n1z = b1x * b2y - b1y * b2x;
        const float n2x = b2y * b3z - b2z * b3y;
        const float n2y = b2z * b3x - b2x * b3z;
        const float n2z = b2x * b3y - b2y * b3x;
        const float b2n = sqrtf(b2x * b2x + b2y * b2y + b2z * b2z + eps);
        const float bux = b2x / b2n, buy = b2y / b2n, buz = b2z / b2n;
        const float m1x = n1y * buz - n1z * buy;
        const float m1y = n1z * bux - n1x * buz;
        const float m1z = n1x * buy - n1y * bux;
        const float yv = m1x * n2x + m1y * n2y + m1z * n2z;
        const float xv = n1x * n2x + n1y * n2y + n1z * n2z + eps;
        const float phi = atan2f(yv, xv);
        return Kc * (1.0f + cosf(per * phi - x0));
    }
}

__device__ __forceinline__ fv4 unpack_pos(unsigned long long a) {
    const unsigned lo = (unsigned)a, hi = (unsigned)(a >> 32);
    fv4 r;
    r.x = (float)(int)(lo & 0x7FFFu) * (1.0f / 512.0f) - 32.0f;
    r.y = (float)(int)((lo >> 15) & 0x7FFFu) * (1.0f / 512.0f) - 32.0f;
    r.z = (float)(int)(((hi & 0xFFFu) << 2) | (lo >> 30)) * (1.0f / 256.0f) - 32.0f;
    r.w = 0.0f;
    return r;
}
__device__ __forceinline__ unsigned unpack_uid(unsigned long long a) {
    return (unsigned)(a >> 32) >> 12;
}
__device__ __forceinline__ float hv_energy(unsigned w, int nat,
                                           fv4 R0, fv4 R1, fv4 R2, fv4 R3) {
    const float Kc  = (float)(w & 0xFFu) * (1.0f / 64.0f);
    const float x0  = (float)((w >> 8) & 0x3Fu) * (1.0f / 32.0f);
    const float per = (float)((w >> 14) + 1u);
    return energy_row(nat, R0, R1, R2, R3, Kc, x0, per);
}

// ================= LDS-slab main kernel (r11 structure, plain stores) =================
__launch_bounds__(LDS_BLK, 1)
__global__ void cart_lds_kernel(
    const unsigned long long* __restrict__ at8,    // [P*A]
    const unsigned short* __restrict__ hv2tab,     // [H]
    const int* __restrict__ subs,                  // [NSUB,4]
    const int* __restrict__ offs,                  // [P+1]
    float*     __restrict__ partials,              // [P*nchunk]
    int nchunk, int nsub, int P, int A, unsigned H)
{
    __shared__ unsigned long long slab[16384];     // 128 KiB
    __shared__ float s_w[LDS_BLK / 64];

    const int p = blockIdx.x / nchunk;
    const int c = blockIdx.x % nchunk;
    const int lo = (p == 0) ? 0 : offs[p];
    const int hi = (p == P - 1) ? nsub : offs[p + 1];

    // Stage pose slab (coalesced, 16B vector loads).
    const unsigned long long* __restrict__ src = at8 + (long)p * A;
    if ((A & 1) == 0) {
        const int A2 = A >> 1;
        for (int t = threadIdx.x; t < A2; t += LDS_BLK)
            reinterpret_cast<llv2*>(slab)[t] =
                reinterpret_cast<const llv2*>(src)[t];
    } else {
        for (int t = threadIdx.x; t < A; t += LDS_BLK)
            slab[t] = src[t];
    }
    __syncthreads();

    const unsigned hmask = H - 1u;
    const bool pow2 = (H & hmask) == 0u;
    const int RPB = LDS_BLK * LDS_ITER;

    float acc = 0.0f;
    for (int start = lo + c * RPB; start < hi; start += nchunk * RPB) {
        #pragma unroll
        for (int k = 0; k < LDS_ITER; ++k) {
            const int row = start + k * LDS_BLK + (int)threadIdx.x;
            const bool a = row < hi;
            const int rr = a ? row : (nsub - 1);
            const iv4 sg = __builtin_nontemporal_load(
                reinterpret_cast<const iv4*>(subs) + rr);
            const int nat = (sg.x >= 0) + (sg.y >= 0) + (sg.z >= 0) + (sg.w >= 0);
            const unsigned long long a0 = slab[max(sg.x, 0)];
            const unsigned long long a1 = slab[max(sg.y, 0)];
            const unsigned long long a2 = (sg.z >= 0) ? slab[sg.z] : 0ull;
            const unsigned long long a3 = (sg.w >= 0) ? slab[sg.w] : 0ull;
            const unsigned u0 = (sg.x >= 0) ? unpack_uid(a0) : 0u;
            const unsigned u1 = (sg.y >= 0) ? unpack_uid(a1) : 0u;
            const unsigned u2 = (sg.z >= 0) ? unpack_uid(a2) : 0u;
            const unsigned u3 = (sg.w >= 0) ? unpack_uid(a3) : 0u;
            const unsigned kk = u0 * 3u + u1 * 5u + u2 * 7u + u3 * 11u + (unsigned)nat;
            const unsigned key = pow2 ? (kk & hmask) : (kk % H);
            const unsigned w = (unsigned)hv2tab[key];
            const float e = hv_energy(w, nat, unpack_pos(a0), unpack_pos(a1),
                                      unpack_pos(a2), unpack_pos(a3));
            acc += a ? e : 0.0f;
        }
    }

    // Block reduction -> one plain store per block.
    #pragma unroll
    for (int off = 1; off < 64; off <<= 1) acc += __shfl_xor(acc, off);
    const int wid = threadIdx.x >> 6, lane = threadIdx.x & 63;
    if (lane == 0) s_w[wid] = acc;
    __syncthreads();
    if (threadIdx.x == 0) {
        float s = 0.0f;
        #pragma unroll
        for (int w = 0; w < LDS_BLK / 64; ++w) s += s_w[w];
        partials[blockIdx.x] = s;
    }
}

// Final for LDS path: P blocks x 64 threads; each sums its pose's nchunk partials.
__global__ void final_pose_kernel(const float* __restrict__ partials, int nchunk,
                                  float* __restrict__ out)
{
    const int p = blockIdx.x;
    float s = 0.0f;
    for (int c = threadIdx.x; c < nchunk; c += 64)
        s += partials[(long)p * nchunk + c];
    #pragma unroll
    for (int off = 1; off < 64; off <<= 1) s += __shfl_xor(s, off);
    if (threadIdx.x == 0) out[p] = s;
}

// ================= round-9 kernel (fallback when slab > LDS) =================
__launch_bounds__(256)
__global__ void cart_main_kernel(
    const unsigned long long* __restrict__ at8,
    const unsigned short* __restrict__ hv2tab,
    const int* __restrict__ subs,
    const int* __restrict__ offs,
    float*     __restrict__ partials,              // [16, nblk]
    int nblk, int nsub, int P, int A, unsigned H)
{
    __shared__ int s_off[32];
    __shared__ float s_part[64];
    for (int t = threadIdx.x; t < P + 1; t += blockDim.x) s_off[t] = offs[t];
    if (threadIdx.x < 64) s_part[threadIdx.x] = 0.0f;
    __syncthreads();

    const int lane = threadIdx.x & 63;
    const int wid  = threadIdx.x >> 6;
    const int wbase = (blockIdx.x * 4 + wid) * (64 * RPT);
    const unsigned hmask = H - 1u;
    const bool pow2 = (H & hmask) == 0u;

    const int pid_lo = pid_of(s_off, P, min(wbase, nsub - 1));
    const int pid_hi = pid_of(s_off, P, min(wbase + 64 * RPT - 1, nsub - 1));
    const bool wuni = (pid_lo == pid_hi);

    iv4 sg[RPT];
    int nat[RPT], pidr[RPT];
    bool act[RPT];
    unsigned long long a0[RPT], a1[RPT], a2[RPT], a3[RPT];

    #pragma unroll
    for (int k = 0; k < RPT; ++k) {
        const int row = wbase + k * 64 + lane;
        act[k] = row < nsub;
        const int rr = act[k] ? row : nsub - 1;
        sg[k] = __builtin_nontemporal_load(reinterpret_cast<const iv4*>(subs) + rr);
        nat[k] = (sg[k].x >= 0) + (sg[k].y >= 0) + (sg[k].z >= 0) + (sg[k].w >= 0);
        pidr[k] = wuni ? pid_lo : pid_of(s_off, P, rr);
        const unsigned long long* __restrict__ base = at8 + (long)pidr[k] * A;
        a0[k] = base[max(sg[k].x, 0)];
        a1[k] = base[max(sg[k].y, 0)];
        a2[k] = (sg[k].z >= 0) ? base[sg[k].z] : 0ull;
        a3[k] = (sg[k].w >= 0) ? base[sg[k].w] : 0ull;
    }

    unsigned hvw[RPT];
    #pragma unroll
    for (int k = 0; k < RPT; ++k) {
        const unsigned u0 = (sg[k].x >= 0) ? unpack_uid(a0[k]) : 0u;
        const unsigned u1 = (sg[k].y >= 0) ? unpack_uid(a1[k]) : 0u;
        const unsigned u2 = (sg[k].z >= 0) ? unpack_uid(a2[k]) : 0u;
        const unsigned u3 = (sg[k].w >= 0) ? unpack_uid(a3[k]) : 0u;
        const unsigned kk = u0 * 3u + u1 * 5u + u2 * 7u + u3 * 11u + (unsigned)nat[k];
        const unsigned key = pow2 ? (kk & hmask) : (kk % H);
        hvw[k] = (unsigned)hv2tab[key];
    }

    float ek[RPT], esum = 0.0f;
    #pragma unroll
    for (int k = 0; k < RPT; ++k) {
        float e = hv_energy(hvw[k], nat[k], unpack_pos(a0[k]), unpack_pos(a1[k]),
                            unpack_pos(a2[k]), unpack_pos(a3[k]));
        e = act[k] ? e : 0.0f;
        ek[k] = e;
        esum += e;
    }

    if (wuni) {
        #pragma unroll
        for (int off = 1; off < 64; off <<= 1) esum += __shfl_xor(esum, off);
        if (lane == 0) s_part[wid * 16 + pid_lo] += esum;
    } else {
        #pragma unroll
        for (int k = 0; k < RPT; ++k)
            if (act[k]) atomicAdd(&s_part[wid * 16 + pidr[k]], ek[k]);
    }
    __syncthreads();
    if (threadIdx.x < 16) {
        const float p = s_part[threadIdx.x] + s_part[16 + threadIdx.x]
                      + s_part[32 + threadIdx.x] + s_part[48 + threadIdx.x];
        partials[(long)threadIdx.x * nblk + blockIdx.x] = p;
    }
}

__launch_bounds__(256)
__global__ void final_reduce_kernel(const float* __restrict__ partials, int nblk,
                                    float* __restrict__ out)
{
    const int p = blockIdx.x;
    float s = 0.0f;
    for (int j = threadIdx.x; j < nblk; j += blockDim.x)
        s += partials[(long)p * nblk + j];
    #pragma unroll
    for (int off = 1; off < 64; off <<= 1) s += __shfl_xor(s, off);
    __shared__ float sw[4];
    const int wid = threadIdx.x >> 6, lane = threadIdx.x & 63;
    if (lane == 0) sw[wid] = s;
    __syncthreads();
    if (threadIdx.x == 0) out[p] = sw[0] + sw[1] + sw[2] + sw[3];
}

// ---------- fallback path (tiny workspace): direct atomics, full precision ----------
__global__ void init_kernel(float* __restrict__ out, int n) {
    int i = blockIdx.x * blockDim.x + threadIdx.x;
    if (i < n) out[i] = 0.0f;
}
__device__ __forceinline__ float3 ld3(const float* __restrict__ p) {
    return make_float3(p[0], p[1], p[2]);
}
__launch_bounds__(256)
__global__ void cart_bonded_fallback_kernel(
    const float* __restrict__ coords, const int* __restrict__ uids,
    const int* __restrict__ hkeys, const float* __restrict__ hvals,
    const int* __restrict__ subs, const int* __restrict__ offs,
    float* __restrict__ out, int nsub, int P, int A, unsigned H)
{
    __shared__ int s_off[32];
    for (int t = threadIdx.x; t < P + 1; t += blockDim.x) s_off[t] = offs[t];
    __syncthreads();
    const int i = blockIdx.x * blockDim.x + threadIdx.x;
    if (i >= nsub) return;
    const iv4 sg = reinterpret_cast<const iv4*>(subs)[i];
    const int nat = (sg.x >= 0) + (sg.y >= 0) + (sg.z >= 0) + (sg.w >= 0);
    const int pid = pid_of(s_off, P, i);
    const int i0 = max(sg.x, 0), i1 = max(sg.y, 0), i2 = max(sg.z, 0), i3 = max(sg.w, 0);
    const int* ub = uids + (long)pid * A;
    const unsigned u0 = (sg.x >= 0) ? (unsigned)ub[i0] : 0u;
    const unsigned u1 = (sg.y >= 0) ? (unsigned)ub[i1] : 0u;
    const unsigned u2 = (sg.z >= 0) ? (unsigned)ub[i2] : 0u;
    const unsigned u3 = (sg.w >= 0) ? (unsigned)ub[i3] : 0u;
    unsigned k = u0 * 3u + u1 * 5u + u2 * 7u + u3 * 11u + (unsigned)nat;
    const unsigned key = ((H & (H - 1u)) == 0u) ? (k & (H - 1u)) : (k % H);
    const bool hit = (hkeys[key] == (int)key);
    float Kc = 1.0f, x0 = 0.0f, per = 1.0f;
    if (hit) {
        const float* hvp = hvals + 3L * key;
        Kc = hvp[0]; x0 = hvp[1]; per = rintf(hvp[2] * 3.0f) + 1.0f;
    }
    const float* cb = coords + (long)pid * (long)A * 3L;
    fv4 R0, R1, R2, R3;
    float3 q;
    q = ld3(cb + 3L * i0); R0.x = q.x; R0.y = q.y; R0.z = q.z;
    q = ld3(cb + 3L * i1); R1.x = q.x; R1.y = q.y; R1.z = q.z;
    q = ld3(cb + 3L * i2); R2.x = q.x; R2.y = q.y; R2.z = q.z;
    q = ld3(cb + 3L * i3); R3.x = q.x; R3.y = q.y; R3.z = q.z;
    const float e = energy_row(nat, R0, R1, R2, R3, Kc, x0, per);
    atomicAdd(&out[pid], e);
}

extern "C" void kernel_launch(void* const* d_in, const int* in_sizes, int n_in,
                              void* d_out, int out_size, void* d_ws, size_t ws_size,
                              hipStream_t stream) {
    const float* coords = (const float*)d_in[0];
    const int*   uids   = (const int*)d_in[5];
    const int*   hkeys  = (const int*)d_in[6];
    const float* hvals  = (const float*)d_in[7];
    const int*   subs   = (const int*)d_in[8];
    const int*   offs   = (const int*)d_in[9];
    float* out = (float*)d_out;

    const int P    = in_sizes[9] - 1;        // 16
    const int A    = in_sizes[5] / P;        // 16384
    const int H    = in_sizes[6];            // 1<<20
    const int nsub = in_sizes[8] / 4;        // 2,000,000
    const int PA   = P * A;

    // LDS-path geometry
    const int RPB = LDS_BLK * LDS_ITER;                 // 8192
    const int avg = (nsub + P - 1) / max(P, 1);
    int nchunk = (avg + RPB - 1) / RPB;
    if (nchunk < 1) nchunk = 1;
    const int ngrid = P * nchunk;                       // 256 for default shape

    // r9-path geometry
    const int nblk = (nsub + 256 * RPT - 1) / (256 * RPT);

    // ws layout (256-aligned): at8 | hv2tab | partials
    const size_t off_at8  = 0;
    const size_t off_hv2  = off_at8 + (size_t)PA * 8;
    const size_t off_part = (off_hv2 + (size_t)H * 2 + 255) & ~(size_t)255;
    const size_t part_a   = (size_t)ngrid * 4;
    const size_t part_b   = (size_t)16 * nblk * 4;
    const size_t need     = off_part + (part_a > part_b ? part_a : part_b);

    if (ws_size >= need && P >= 1 && P <= 16 && H <= (1 << 20)) {
        unsigned long long* at8      = (unsigned long long*)((char*)d_ws + off_at8);
        unsigned short*     hv2tab   = (unsigned short*)((char*)d_ws + off_hv2);
        float*              partials = (float*)((char*)d_ws + off_part);

        if ((H & 3) == 0 && (PA & 3) == 0)
            prep_vec_kernel<<<1024, 256, 0, stream>>>(coords, uids, hkeys, hvals,
                                                      PA, H, at8, hv2tab);
        else
            prep_kernel<<<4096, 256, 0, stream>>>(coords, uids, hkeys, hvals,
                                                  PA, H, at8, hv2tab);

        if ((size_t)A * 8 <= 131072) {
            cart_lds_kernel<<<ngrid, LDS_BLK, 0, stream>>>(
                at8, hv2tab, subs, offs, partials, nchunk, nsub, P, A, (unsigned)H);
            final_pose_kernel<<<P, 64, 0, stream>>>(partials, nchunk, out);
        } else {
            cart_main_kernel<<<nblk, 256, 0, stream>>>(
                at8, hv2tab, subs, offs, partials, nblk, nsub, P, A, (unsigned)H);
            final_reduce_kernel<<<P, 256, 0, stream>>>(partials, nblk, out);
        }
    } else {
        init_kernel<<<1, 64, 0, stream>>>(out, out_size);
        const int grid = (nsub + 255) / 256;
        cart_bonded_fallback_kernel<<<grid, 256, 0, stream>>>(
            coords, uids, hkeys, hvals, subs, offs, out, nsub, P, A, (unsigned)H);
    }
}

// Round 14
// 37.681 us; speedup vs baseline: 1.2996x; 1.0088x over previous
//
#include <hip/hip_runtime.h>

using iv4 = __attribute__((ext_vector_type(4))) int;
using fv4 = __attribute__((ext_vector_type(4))) float;
using usv4 = __attribute__((ext_vector_type(4))) unsigned short;
using llv2 = __attribute__((ext_vector_type(2))) long long;

#define RPT 2            // fallback kernel: rows per thread
#define LDS_ITER 8       // LDS kernel: rows per thread per stride-step
#define GRP 4            // stage-batch group size (VGPR-bounded)
#define LDS_BLK 1024     // LDS kernel block size

__device__ __forceinline__ int pid_of(const int* __restrict__ s_off, int P, int row) {
    int c = -1;
    for (int k = 0; k <= P; ++k) c += (s_off[k] <= row) ? 1 : 0;
    return min(max(c, 0), P - 1);
}

__device__ __forceinline__ unsigned long long pack_at8(float x, float y, float z,
                                                       int uid_in) {
    int xq = (int)rintf((x + 32.0f) * 512.0f);
    int yq = (int)rintf((y + 32.0f) * 512.0f);
    int zq = (int)rintf((z + 32.0f) * 256.0f);
    xq = min(max(xq, 0), 32767);
    yq = min(max(yq, 0), 32767);
    zq = min(max(zq, 0), 16383);
    const unsigned uid = (unsigned)uid_in & 0xFFFFFu;
    const unsigned lo = (unsigned)xq | ((unsigned)yq << 15) | ((unsigned)(zq & 3) << 30);
    const unsigned hi = (unsigned)(zq >> 2) | (uid << 12);
    return (unsigned long long)lo | ((unsigned long long)hi << 32);
}

__device__ __forceinline__ unsigned short pack_hv2(float Kc, float x0, int per) {
    int kq  = (int)rintf(Kc * 64.0f);
    int xq0 = (int)rintf(x0 * 32.0f);
    kq  = min(max(kq, 0), 255);
    xq0 = min(max(xq0, 0), 63);
    return (unsigned short)((unsigned)kq | ((unsigned)xq0 << 8)
                            | ((unsigned)(per - 1) << 14));
}

// Vectorized prep: 4 entries/thread. Requires H%4==0 && PA%4==0.
__global__ void prep_vec_kernel(const float* __restrict__ coords,
                                const int* __restrict__ uids,
                                const int* __restrict__ hkeys,
                                const float* __restrict__ hvals,
                                int PA, int H,
                                unsigned long long* __restrict__ at8,
                                unsigned short* __restrict__ hv2tab)
{
    const int stride4 = gridDim.x * blockDim.x;
    const int n4 = H >> 2;
    for (int q = blockIdx.x * blockDim.x + threadIdx.x; q < n4; q += stride4) {
        const int t0 = q * 4;
        if (t0 < PA) {
            const fv4 c0 = reinterpret_cast<const fv4*>(coords)[3 * q];
            const fv4 c1 = reinterpret_cast<const fv4*>(coords)[3 * q + 1];
            const fv4 c2 = reinterpret_cast<const fv4*>(coords)[3 * q + 2];
            const iv4 u  = reinterpret_cast<const iv4*>(uids)[q];
            llv2 w0, w1;
            w0.x = (long long)pack_at8(c0.x, c0.y, c0.z, u.x);
            w0.y = (long long)pack_at8(c0.w, c1.x, c1.y, u.y);
            w1.x = (long long)pack_at8(c1.z, c1.w, c2.x, u.z);
            w1.y = (long long)pack_at8(c2.y, c2.z, c2.w, u.w);
            reinterpret_cast<llv2*>(at8)[2 * q]     = w0;
            reinterpret_cast<llv2*>(at8)[2 * q + 1] = w1;
        }
        const iv4 hk = reinterpret_cast<const iv4*>(hkeys)[q];
        const fv4 h0 = reinterpret_cast<const fv4*>(hvals)[3 * q];
        const fv4 h1 = reinterpret_cast<const fv4*>(hvals)[3 * q + 1];
        const fv4 h2 = reinterpret_cast<const fv4*>(hvals)[3 * q + 2];
        usv4 e;
        {
            const bool hit = (hk.x == t0);
            e.x = pack_hv2(hit ? h0.x : 1.0f, hit ? h0.y : 0.0f,
                           hit ? (int)(rintf(h0.z * 3.0f) + 1.0f) : 1);
        }
        {
            const bool hit = (hk.y == t0 + 1);
            e.y = pack_hv2(hit ? h0.w : 1.0f, hit ? h1.x : 0.0f,
                           hit ? (int)(rintf(h1.y * 3.0f) + 1.0f) : 1);
        }
        {
            const bool hit = (hk.z == t0 + 2);
            e.z = pack_hv2(hit ? h1.z : 1.0f, hit ? h1.w : 0.0f,
                           hit ? (int)(rintf(h2.x * 3.0f) + 1.0f) : 1);
        }
        {
            const bool hit = (hk.w == t0 + 3);
            e.w = pack_hv2(hit ? h2.y : 1.0f, hit ? h2.z : 0.0f,
                           hit ? (int)(rintf(h2.w * 3.0f) + 1.0f) : 1);
        }
        reinterpret_cast<usv4*>(hv2tab)[q] = e;
    }
}

// Scalar prep (general shapes).
__global__ void prep_kernel(const float* __restrict__ coords,
                            const int* __restrict__ uids,
                            const int* __restrict__ hkeys,
                            const float* __restrict__ hvals,
                            int PA, int H,
                            unsigned long long* __restrict__ at8,
                            unsigned short* __restrict__ hv2tab)
{
    const int stride = gridDim.x * blockDim.x;
    for (int t = blockIdx.x * blockDim.x + threadIdx.x; t < H; t += stride) {
        if (t < PA)
            at8[t] = pack_at8(coords[3 * t], coords[3 * t + 1], coords[3 * t + 2],
                              uids[t]);
        const bool hit = (hkeys[t] == t);
        hv2tab[t] = pack_hv2(hit ? hvals[3 * t] : 1.0f,
                             hit ? hvals[3 * t + 1] : 0.0f,
                             hit ? (int)(rintf(hvals[3 * t + 2] * 3.0f) + 1.0f) : 1);
    }
}

__device__ __forceinline__ float energy_row(int nat, fv4 R0, fv4 R1, fv4 R2, fv4 R3,
                                            float Kc, float x0, float per)
{
    const float eps = 1e-6f;
    if (nat == 2) {
        const float dx = R1.x - R0.x, dy = R1.y - R0.y, dz = R1.z - R0.z;
        const float d = sqrtf(dx * dx + dy * dy + dz * dz + eps);
        const float t = d - x0;
        return Kc * t * t;
    } else if (nat == 3) {
        const float ux = R0.x - R1.x, uy = R0.y - R1.y, uz = R0.z - R1.z;
        const float vx = R2.x - R1.x, vy = R2.y - R1.y, vz = R2.z - R1.z;
        const float uv = ux * vx + uy * vy + uz * vz;
        const float uu = ux * ux + uy * uy + uz * uz;
        const float vv = vx * vx + vy * vy + vz * vz;
        float cosang = uv / (sqrtf(uu + eps) * sqrtf(vv + eps));
        cosang = fminf(fmaxf(cosang, -1.0f + 1e-6f), 1.0f - 1e-6f);
        const float t = acosf(cosang) - x0;
        return Kc * t * t;
    } else {
        const float b1x = R1.x - R0.x, b1y = R1.y - R0.y, b1z = R1.z - R0.z;
        const float b2x = R2.x - R1.x, b2y = R2.y - R1.y, b2z = R2.z - R1.z;
        const float b3x = R3.x - R2.x, b3y = R3.y - R2.y, b3z = R3.z - R2.z;
        const float n1x = b1y * b2z - b1z * b2y;
        const float n1y = b1z * b2x - b1x * b2z;
        const float n1z = b1x * b2y - b1y * b2x;
        const float n2x = b2y * b3z - b2z * b3y;
        const float n2y = b2z * b3x - b2x * b3z;
        const float n2z = b2x * b3y - b2y * b3x;
        const float b2n = sqrtf(b2x * b2x + b2y * b2y + b2z * b2z + eps);
        const float bux = b2x / b2n, buy = b2y / b2n, buz = b2z / b2n;
        const float m1x = n1y * buz - n1z * buy;
        const float m1y = n1z * bux - n1x * buz;
        const float m1z = n1x * buy - n1y * bux;
        const float yv = m1x * n2x + m1y * n2y + m1z * n2z;
        const float xv = n1x * n2x + n1y * n2y + n1z * n2z + eps;
        const float phi = atan2f(yv, xv);
        return Kc * (1.0f + cosf(per * phi - x0));
    }
}

__device__ __forceinline__ fv4 unpack_pos(unsigned long long a) {
    const unsigned lo = (unsigned)a, hi = (unsigned)(a >> 32);
    fv4 r;
    r.x = (float)(int)(lo & 0x7FFFu) * (1.0f / 512.0f) - 32.0f;
    r.y = (float)(int)((lo >> 15) & 0x7FFFu) * (1.0f / 512.0f) - 32.0f;
    r.z = (float)(int)(((hi & 0xFFFu) << 2) | (lo >> 30)) * (1.0f / 256.0f) - 32.0f;
    r.w = 0.0f;
    return r;
}
__device__ __forceinline__ unsigned unpack_uid(unsigned long long a) {
    return (unsigned)(a >> 32) >> 12;
}
__device__ __forceinline__ float hv_energy(unsigned w, int nat,
                                           fv4 R0, fv4 R1, fv4 R2, fv4 R3) {
    const float Kc  = (float)(w & 0xFFu) * (1.0f / 64.0f);
    const float x0  = (float)((w >> 8) & 0x3Fu) * (1.0f / 32.0f);
    const float per = (float)((w >> 14) + 1u);
    return energy_row(nat, R0, R1, R2, R3, Kc, x0, per);
}

// ================= LDS-slab main kernel (stage-batched inner loop) =================
__launch_bounds__(LDS_BLK, 1)
__global__ void cart_lds_kernel(
    const unsigned long long* __restrict__ at8,    // [P*A]
    const unsigned short* __restrict__ hv2tab,     // [H]
    const int* __restrict__ subs,                  // [NSUB,4]
    const int* __restrict__ offs,                  // [P+1]
    float*     __restrict__ partials,              // [P*nchunk]
    int nchunk, int nsub, int P, int A, unsigned H)
{
    __shared__ unsigned long long slab[16384];     // 128 KiB
    __shared__ float s_w[LDS_BLK / 64];

    const int p = blockIdx.x / nchunk;
    const int c = blockIdx.x % nchunk;
    const int lo = (p == 0) ? 0 : offs[p];
    const int hi = (p == P - 1) ? nsub : offs[p + 1];

    // Stage pose slab (coalesced, 16B vector loads).
    const unsigned long long* __restrict__ src = at8 + (long)p * A;
    if ((A & 1) == 0) {
        const int A2 = A >> 1;
        for (int t = threadIdx.x; t < A2; t += LDS_BLK)
            reinterpret_cast<llv2*>(slab)[t] =
                reinterpret_cast<const llv2*>(src)[t];
    } else {
        for (int t = threadIdx.x; t < A; t += LDS_BLK)
            slab[t] = src[t];
    }
    __syncthreads();

    const unsigned hmask = H - 1u;
    const bool pow2 = (H & hmask) == 0u;
    const int RPB = LDS_BLK * LDS_ITER;

    float acc = 0.0f;
    for (int start = lo + c * RPB; start < hi; start += nchunk * RPB) {
        #pragma unroll
        for (int g = 0; g < LDS_ITER / GRP; ++g) {
            // Pass 1: issue GRP coalesced subs loads (independent VMEM chains).
            iv4 sg[GRP];
            #pragma unroll
            for (int k = 0; k < GRP; ++k) {
                const int row = start + (g * GRP + k) * LDS_BLK + (int)threadIdx.x;
                const int rr = (row < hi) ? row : (nsub - 1);
                sg[k] = __builtin_nontemporal_load(
                    reinterpret_cast<const iv4*>(subs) + rr);
            }
            // Pass 2: issue 4*GRP slab ds_reads.
            unsigned long long a0[GRP], a1[GRP], a2[GRP], a3[GRP];
            #pragma unroll
            for (int k = 0; k < GRP; ++k) {
                a0[k] = slab[max(sg[k].x, 0)];
                a1[k] = slab[max(sg[k].y, 0)];
                a2[k] = (sg[k].z >= 0) ? slab[sg[k].z] : 0ull;
                a3[k] = (sg[k].w >= 0) ? slab[sg[k].w] : 0ull;
            }
            // Pass 3: keys + GRP hash probes (independent L2 chains).
            unsigned hvw[GRP];
            int natv[GRP];
            #pragma unroll
            for (int k = 0; k < GRP; ++k) {
                const int nat = (sg[k].x >= 0) + (sg[k].y >= 0)
                              + (sg[k].z >= 0) + (sg[k].w >= 0);
                natv[k] = nat;
                const unsigned u0 = (sg[k].x >= 0) ? unpack_uid(a0[k]) : 0u;
                const unsigned u1 = (sg[k].y >= 0) ? unpack_uid(a1[k]) : 0u;
                const unsigned u2 = (sg[k].z >= 0) ? unpack_uid(a2[k]) : 0u;
                const unsigned u3 = (sg[k].w >= 0) ? unpack_uid(a3[k]) : 0u;
                const unsigned kk = u0 * 3u + u1 * 5u + u2 * 7u + u3 * 11u
                                  + (unsigned)nat;
                const unsigned key = pow2 ? (kk & hmask) : (kk % H);
                hvw[k] = (unsigned)hv2tab[key];
            }
            // Pass 4: energies.
            #pragma unroll
            for (int k = 0; k < GRP; ++k) {
                const int row = start + (g * GRP + k) * LDS_BLK + (int)threadIdx.x;
                const float e = hv_energy(hvw[k], natv[k],
                                          unpack_pos(a0[k]), unpack_pos(a1[k]),
                                          unpack_pos(a2[k]), unpack_pos(a3[k]));
                acc += (row < hi) ? e : 0.0f;
            }
        }
    }

    // Block reduction -> one plain store per block.
    #pragma unroll
    for (int off = 1; off < 64; off <<= 1) acc += __shfl_xor(acc, off);
    const int wid = threadIdx.x >> 6, lane = threadIdx.x & 63;
    if (lane == 0) s_w[wid] = acc;
    __syncthreads();
    if (threadIdx.x == 0) {
        float s = 0.0f;
        #pragma unroll
        for (int w = 0; w < LDS_BLK / 64; ++w) s += s_w[w];
        partials[blockIdx.x] = s;
    }
}

// Final for LDS path: P blocks x 64 threads.
__global__ void final_pose_kernel(const float* __restrict__ partials, int nchunk,
                                  float* __restrict__ out)
{
    const int p = blockIdx.x;
    float s = 0.0f;
    for (int c = threadIdx.x; c < nchunk; c += 64)
        s += partials[(long)p * nchunk + c];
    #pragma unroll
    for (int off = 1; off < 64; off <<= 1) s += __shfl_xor(s, off);
    if (threadIdx.x == 0) out[p] = s;
}

// ================= round-9 kernel (fallback when slab > LDS) =================
__launch_bounds__(256)
__global__ void cart_main_kernel(
    const unsigned long long* __restrict__ at8,
    const unsigned short* __restrict__ hv2tab,
    const int* __restrict__ subs,
    const int* __restrict__ offs,
    float*     __restrict__ partials,              // [16, nblk]
    int nblk, int nsub, int P, int A, unsigned H)
{
    __shared__ int s_off[32];
    __shared__ float s_part[64];
    for (int t = threadIdx.x; t < P + 1; t += blockDim.x) s_off[t] = offs[t];
    if (threadIdx.x < 64) s_part[threadIdx.x] = 0.0f;
    __syncthreads();

    const int lane = threadIdx.x & 63;
    const int wid  = threadIdx.x >> 6;
    const int wbase = (blockIdx.x * 4 + wid) * (64 * RPT);
    const unsigned hmask = H - 1u;
    const bool pow2 = (H & hmask) == 0u;

    const int pid_lo = pid_of(s_off, P, min(wbase, nsub - 1));
    const int pid_hi = pid_of(s_off, P, min(wbase + 64 * RPT - 1, nsub - 1));
    const bool wuni = (pid_lo == pid_hi);

    iv4 sg[RPT];
    int nat[RPT], pidr[RPT];
    bool act[RPT];
    unsigned long long a0[RPT], a1[RPT], a2[RPT], a3[RPT];

    #pragma unroll
    for (int k = 0; k < RPT; ++k) {
        const int row = wbase + k * 64 + lane;
        act[k] = row < nsub;
        const int rr = act[k] ? row : nsub - 1;
        sg[k] = __builtin_nontemporal_load(reinterpret_cast<const iv4*>(subs) + rr);
        nat[k] = (sg[k].x >= 0) + (sg[k].y >= 0) + (sg[k].z >= 0) + (sg[k].w >= 0);
        pidr[k] = wuni ? pid_lo : pid_of(s_off, P, rr);
        const unsigned long long* __restrict__ base = at8 + (long)pidr[k] * A;
        a0[k] = base[max(sg[k].x, 0)];
        a1[k] = base[max(sg[k].y, 0)];
        a2[k] = (sg[k].z >= 0) ? base[sg[k].z] : 0ull;
        a3[k] = (sg[k].w >= 0) ? base[sg[k].w] : 0ull;
    }

    unsigned hvw[RPT];
    #pragma unroll
    for (int k = 0; k < RPT; ++k) {
        const unsigned u0 = (sg[k].x >= 0) ? unpack_uid(a0[k]) : 0u;
        const unsigned u1 = (sg[k].y >= 0) ? unpack_uid(a1[k]) : 0u;
        const unsigned u2 = (sg[k].z >= 0) ? unpack_uid(a2[k]) : 0u;
        const unsigned u3 = (sg[k].w >= 0) ? unpack_uid(a3[k]) : 0u;
        const unsigned kk = u0 * 3u + u1 * 5u + u2 * 7u + u3 * 11u + (unsigned)nat[k];
        const unsigned key = pow2 ? (kk & hmask) : (kk % H);
        hvw[k] = (unsigned)hv2tab[key];
    }

    float ek[RPT], esum = 0.0f;
    #pragma unroll
    for (int k = 0; k < RPT; ++k) {
        float e = hv_energy(hvw[k], nat[k], unpack_pos(a0[k]), unpack_pos(a1[k]),
                            unpack_pos(a2[k]), unpack_pos(a3[k]));
        e = act[k] ? e : 0.0f;
        ek[k] = e;
        esum += e;
    }

    if (wuni) {
        #pragma unroll
        for (int off = 1; off < 64; off <<= 1) esum += __shfl_xor(esum, off);
        if (lane == 0) s_part[wid * 16 + pid_lo] += esum;
    } else {
        #pragma unroll
        for (int k = 0; k < RPT; ++k)
            if (act[k]) atomicAdd(&s_part[wid * 16 + pidr[k]], ek[k]);
    }
    __syncthreads();
    if (threadIdx.x < 16) {
        const float p = s_part[threadIdx.x] + s_part[16 + threadIdx.x]
                      + s_part[32 + threadIdx.x] + s_part[48 + threadIdx.x];
        partials[(long)threadIdx.x * nblk + blockIdx.x] = p;
    }
}

__launch_bounds__(256)
__global__ void final_reduce_kernel(const float* __restrict__ partials, int nblk,
                                    float* __restrict__ out)
{
    const int p = blockIdx.x;
    float s = 0.0f;
    for (int j = threadIdx.x; j < nblk; j += blockDim.x)
        s += partials[(long)p * nblk + j];
    #pragma unroll
    for (int off = 1; off < 64; off <<= 1) s += __shfl_xor(s, off);
    __shared__ float sw[4];
    const int wid = threadIdx.x >> 6, lane = threadIdx.x & 63;
    if (lane == 0) sw[wid] = s;
    __syncthreads();
    if (threadIdx.x == 0) out[p] = sw[0] + sw[1] + sw[2] + sw[3];
}

// ---------- fallback path (tiny workspace): direct atomics, full precision ----------
__global__ void init_kernel(float* __restrict__ out, int n) {
    int i = blockIdx.x * blockDim.x + threadIdx.x;
    if (i < n) out[i] = 0.0f;
}
__device__ __forceinline__ float3 ld3(const float* __restrict__ p) {
    return make_float3(p[0], p[1], p[2]);
}
__launch_bounds__(256)
__global__ void cart_bonded_fallback_kernel(
    const float* __restrict__ coords, const int* __restrict__ uids,
    const int* __restrict__ hkeys, const float* __restrict__ hvals,
    const int* __restrict__ subs, const int* __restrict__ offs,
    float* __restrict__ out, int nsub, int P, int A, unsigned H)
{
    __shared__ int s_off[32];
    for (int t = threadIdx.x; t < P + 1; t += blockDim.x) s_off[t] = offs[t];
    __syncthreads();
    const int i = blockIdx.x * blockDim.x + threadIdx.x;
    if (i >= nsub) return;
    const iv4 sg = reinterpret_cast<const iv4*>(subs)[i];
    const int nat = (sg.x >= 0) + (sg.y >= 0) + (sg.z >= 0) + (sg.w >= 0);
    const int pid = pid_of(s_off, P, i);
    const int i0 = max(sg.x, 0), i1 = max(sg.y, 0), i2 = max(sg.z, 0), i3 = max(sg.w, 0);
    const int* ub = uids + (long)pid * A;
    const unsigned u0 = (sg.x >= 0) ? (unsigned)ub[i0] : 0u;
    const unsigned u1 = (sg.y >= 0) ? (unsigned)ub[i1] : 0u;
    const unsigned u2 = (sg.z >= 0) ? (unsigned)ub[i2] : 0u;
    const unsigned u3 = (sg.w >= 0) ? (unsigned)ub[i3] : 0u;
    unsigned k = u0 * 3u + u1 * 5u + u2 * 7u + u3 * 11u + (unsigned)nat;
    const unsigned key = ((H & (H - 1u)) == 0u) ? (k & (H - 1u)) : (k % H);
    const bool hit = (hkeys[key] == (int)key);
    float Kc = 1.0f, x0 = 0.0f, per = 1.0f;
    if (hit) {
        const float* hvp = hvals + 3L * key;
        Kc = hvp[0]; x0 = hvp[1]; per = rintf(hvp[2] * 3.0f) + 1.0f;
    }
    const float* cb = coords + (long)pid * (long)A * 3L;
    fv4 R0, R1, R2, R3;
    float3 q;
    q = ld3(cb + 3L * i0); R0.x = q.x; R0.y = q.y; R0.z = q.z;
    q = ld3(cb + 3L * i1); R1.x = q.x; R1.y = q.y; R1.z = q.z;
    q = ld3(cb + 3L * i2); R2.x = q.x; R2.y = q.y; R2.z = q.z;
    q = ld3(cb + 3L * i3); R3.x = q.x; R3.y = q.y; R3.z = q.z;
    const float e = energy_row(nat, R0, R1, R2, R3, Kc, x0, per);
    atomicAdd(&out[pid], e);
}

extern "C" void kernel_launch(void* const* d_in, const int* in_sizes, int n_in,
                              void* d_out, int out_size, void* d_ws, size_t ws_size,
                              hipStream_t stream) {
    const float* coords = (const float*)d_in[0];
    const int*   uids   = (const int*)d_in[5];
    const int*   hkeys  = (const int*)d_in[6];
    const float* hvals  = (const float*)d_in[7];
    const int*   subs   = (const int*)d_in[8];
    const int*   offs   = (const int*)d_in[9];
    float* out = (float*)d_out;

    const int P    = in_sizes[9] - 1;        // 16
    const int A    = in_sizes[5] / P;        // 16384
    const int H    = in_sizes[6];            // 1<<20
    const int nsub = in_sizes[8] / 4;        // 2,000,000
    const int PA   = P * A;

    // LDS-path geometry
    const int RPB = LDS_BLK * LDS_ITER;                 // 8192
    const int avg = (nsub + P - 1) / max(P, 1);
    int nchunk = (avg + RPB - 1) / RPB;
    if (nchunk < 1) nchunk = 1;
    const int ngrid = P * nchunk;                       // 256 for default shape

    // r9-path geometry
    const int nblk = (nsub + 256 * RPT - 1) / (256 * RPT);

    // ws layout (256-aligned): at8 | hv2tab | partials
    const size_t off_at8  = 0;
    const size_t off_hv2  = off_at8 + (size_t)PA * 8;
    const size_t off_part = (off_hv2 + (size_t)H * 2 + 255) & ~(size_t)255;
    const size_t part_a   = (size_t)ngrid * 4;
    const size_t part_b   = (size_t)16 * nblk * 4;
    const size_t need     = off_part + (part_a > part_b ? part_a : part_b);

    if (ws_size >= need && P >= 1 && P <= 16 && H <= (1 << 20)) {
        unsigned long long* at8      = (unsigned long long*)((char*)d_ws + off_at8);
        unsigned short*     hv2tab   = (unsigned short*)((char*)d_ws + off_hv2);
        float*              partials = (float*)((char*)d_ws + off_part);

        if ((H & 3) == 0 && (PA & 3) == 0)
            prep_vec_kernel<<<1024, 256, 0, stream>>>(coords, uids, hkeys, hvals,
                                                      PA, H, at8, hv2tab);
        else
            prep_kernel<<<4096, 256, 0, stream>>>(coords, uids, hkeys, hvals,
                                                  PA, H, at8, hv2tab);

        if ((size_t)A * 8 <= 131072) {
            cart_lds_kernel<<<ngrid, LDS_BLK, 0, stream>>>(
                at8, hv2tab, subs, offs, partials, nchunk, nsub, P, A, (unsigned)H);
            final_pose_kernel<<<P, 64, 0, stream>>>(partials, nchunk, out);
        } else {
            cart_main_kernel<<<nblk, 256, 0, stream>>>(
                at8, hv2tab, subs, offs, partials, nblk, nsub, P, A, (unsigned)H);
            final_reduce_kernel<<<P, 256, 0, stream>>>(partials, nblk, out);
        }
    } else {
        init_kernel<<<1, 64, 0, stream>>>(out, out_size);
        const int grid = (nsub + 255) / 256;
        cart_bonded_fallback_kernel<<<grid, 256, 0, stream>>>(
            coords, uids, hkeys, hvals, subs, offs, out, nsub, P, A, (unsigned)H);
    }
}